// Round 8
// baseline (48.386 us; speedup 1.0000x reference)
//
#include <hip/hip_runtime.h>

#define COLS 8192
#define TPB  512

// LDS-only barrier: waits LDS ops, lets global stores stay in flight.
__device__ __forceinline__ void bar_lds() {
    asm volatile("s_waitcnt lgkmcnt(0)" ::: "memory");
    __builtin_amdgcn_sched_barrier(0);
    __builtin_amdgcn_s_barrier();
    __builtin_amdgcn_sched_barrier(0);
}

// ---------------------------------------------------------------------------
// Kernel A: analysis lev0..3 (all waves) + lev4..7 analysis & synth7..4 tail
// (wave 0 only; waves 1..7 exit early so the CU can start the next block).
// Outputs: d0..d7+approx -> out_coef; rec4 (512) -> out_rec[row][512..1024).
// ---------------------------------------------------------------------------
__global__ __launch_bounds__(TPB) void despawn_analysis(
    const float* __restrict__ x, const float* __restrict__ scaling,
    float* __restrict__ out, int rows)
{
    __shared__ __align__(16) float LA[4096];  // a0 ; tail scratch P/Q/Y
    __shared__ __align__(16) float LB[2048];  // a1 ; a3 in [0..512)
    __shared__ float filt[32];

    const int row = blockIdx.x;
    const int tid = threadIdx.x;
    if (tid < 32) filt[tid] = scaling[tid];
    bar_lds();

    const float* __restrict__ xg       = x + (size_t)row * COLS;
    float* __restrict__       out_rec  = out + (size_t)row * COLS;
    float* __restrict__       out_coef = out + (size_t)rows * COLS + (size_t)row * COLS;

    // ---- analysis level 0 (global float4, 4 outputs/thread) ----
    {
        const float h0 = filt[0], h1 = filt[1], h2 = filt[2], h3 = filt[3];
        const float g0 = h3, g1 = -h2, g2 = h1, g3 = -h0;
        const float4* __restrict__ xg4 = reinterpret_cast<const float4*>(xg);
        const int q8 = COLS / 8, qm = COLS / 4 - 1;
        for (int i = tid; i < q8; i += TPB) {
            const float4 va = xg4[(2 * i - 1) & qm];
            const float4 vb = xg4[2 * i];
            const float4 vc = xg4[2 * i + 1];
            float4 dv, av;
            dv.x = g0*vb.x + g1*va.w + g2*va.z + g3*va.y;
            av.x = h0*vb.x + h1*va.w + h2*va.z + h3*va.y;
            dv.y = g0*vb.z + g1*vb.y + g2*vb.x + g3*va.w;
            av.y = h0*vb.z + h1*vb.y + h2*vb.x + h3*va.w;
            dv.z = g0*vc.x + g1*vb.w + g2*vb.z + g3*vb.y;
            av.z = h0*vc.x + h1*vb.w + h2*vb.z + h3*vb.y;
            dv.w = g0*vc.z + g1*vc.y + g2*vc.x + g3*vb.w;
            av.w = h0*vc.z + h1*vc.y + h2*vc.x + h3*vb.w;
            reinterpret_cast<float4*>(out_coef)[i] = dv;   // stays in flight
            reinterpret_cast<float4*>(LA)[i]       = av;
        }
        bar_lds();
    }

    // ---- analysis levels 1..3 (LDS float4) ----
    // lev1: LA(4096)->LB(2048)  lev2: LB->LA(1024)  lev3: LA->LB(512)
    {
        int n = 4096, coff = 4096;
        float* cur = LA;
        float* nxt = LB;
        for (int lev = 1; lev <= 3; ++lev) {
            const float h0 = filt[4*lev+0], h1 = filt[4*lev+1],
                        h2 = filt[4*lev+2], h3 = filt[4*lev+3];
            const float g0 = h3, g1 = -h2, g2 = h1, g3 = -h0;
            const int half = n >> 1, qq = half >> 2, qm = (n >> 2) - 1;
            const float4* c4 = reinterpret_cast<const float4*>(cur);
            float4* o4 = reinterpret_cast<float4*>(out_coef + coff);
            float4* n4 = reinterpret_cast<float4*>(nxt);
            for (int p = tid; p < qq; p += TPB) {
                const float4 va = c4[(2 * p - 1) & qm];
                const float4 vb = c4[2 * p];
                const float4 vc = c4[2 * p + 1];
                float4 dv, av;
                dv.x = g0*vb.x + g1*va.w + g2*va.z + g3*va.y;
                av.x = h0*vb.x + h1*va.w + h2*va.z + h3*va.y;
                dv.y = g0*vb.z + g1*vb.y + g2*vb.x + g3*va.w;
                av.y = h0*vb.z + h1*vb.y + h2*vb.x + h3*va.w;
                dv.z = g0*vc.x + g1*vb.w + g2*vb.z + g3*vb.y;
                av.z = h0*vc.x + h1*vb.w + h2*vb.z + h3*vb.y;
                dv.w = g0*vc.z + g1*vc.y + g2*vc.x + g3*vb.w;
                av.w = h0*vc.z + h1*vc.y + h2*vc.x + h3*vb.w;
                o4[p] = dv;
                n4[p] = av;
            }
            bar_lds();
            coff += half;
            n = half;
            float* t = cur; cur = nxt; nxt = t;
        }
    }
    // a3 (512) in LB[0..512)

    if (tid >= 64) return;   // waves 1..7 done; wave 0 runs the tail

    // ---- wave-0 tail ----
    float* P = LA;            // 512
    float* Q = LA + 512;      // 512
    float* Y = LA + 1024;     // d4@0(256) d5@256(128) d6@384(64) d7@448(32) ap@480(32)
    const int lane = tid;

    // analysis lev4: a3(LB,512) -> d4, a4
    {
        const float h0=filt[16],h1=filt[17],h2=filt[18],h3=filt[19];
        const float g0=h3,g1=-h2,g2=h1,g3=-h0;
        for (int i = lane; i < 256; i += 64) {
            const int b = 2*i;
            const float x0=LB[b], x1=LB[(b-1)&511], x2=LB[(b-2)&511], x3=LB[(b-3)&511];
            const float d = g0*x0+g1*x1+g2*x2+g3*x3;
            Y[i] = d; out_coef[7680+i] = d;
            P[i] = h0*x0+h1*x1+h2*x2+h3*x3;
        }
        __builtin_amdgcn_wave_barrier();
    }
    // lev5: a4(P,256) -> d5, a5(Q)
    {
        const float h0=filt[20],h1=filt[21],h2=filt[22],h3=filt[23];
        const float g0=h3,g1=-h2,g2=h1,g3=-h0;
        for (int i = lane; i < 128; i += 64) {
            const int b = 2*i;
            const float x0=P[b], x1=P[(b-1)&255], x2=P[(b-2)&255], x3=P[(b-3)&255];
            const float d = g0*x0+g1*x1+g2*x2+g3*x3;
            Y[256+i] = d; out_coef[7936+i] = d;
            Q[i] = h0*x0+h1*x1+h2*x2+h3*x3;
        }
        __builtin_amdgcn_wave_barrier();
    }
    // lev6: a5(Q,128) -> d6, a6(P[0..64))
    {
        const float h0=filt[24],h1=filt[25],h2=filt[26],h3=filt[27];
        const float g0=h3,g1=-h2,g2=h1,g3=-h0;
        if (lane < 64) {
            const int i = lane, b = 2*i;
            const float x0=Q[b], x1=Q[(b-1)&127], x2=Q[(b-2)&127], x3=Q[(b-3)&127];
            const float d = g0*x0+g1*x1+g2*x2+g3*x3;
            Y[384+i] = d; out_coef[8064+i] = d;
            P[i] = h0*x0+h1*x1+h2*x2+h3*x3;
        }
        __builtin_amdgcn_wave_barrier();
    }
    // lev7: a6(P,64) -> d7, approx
    {
        const float h0=filt[28],h1=filt[29],h2=filt[30],h3=filt[31];
        const float g0=h3,g1=-h2,g2=h1,g3=-h0;
        if (lane < 32) {
            const int i = lane, b = 2*i;
            const float x0=P[b], x1=P[(b-1)&63], x2=P[(b-2)&63], x3=P[(b-3)&63];
            const float d = g0*x0+g1*x1+g2*x2+g3*x3;
            const float a = h0*x0+h1*x1+h2*x2+h3*x3;
            Y[448+i] = d; out_coef[8128+i] = d;
            Y[480+i] = a; out_coef[8160+i] = a;
        }
        __builtin_amdgcn_wave_barrier();
    }
    // synth lev7: d7(Y+448), ap(Y+480) -> rec7(64) in Q[0..64)
    {
        const float h0=filt[28],h1=filt[29],h2=filt[30],h3=filt[31];
        const float g0=h3,g1=-h2,g2=h1,g3=-h0;
        if (lane < 32) {
            const int j = lane;
            const float dj=Y[448+j], dj1=Y[448+((j+1)&31)], dj2=Y[448+((j+2)&31)];
            const float aj=Y[480+j], aj1=Y[480+((j+1)&31)], aj2=Y[480+((j+2)&31)];
            Q[2*j]   = g0*dj  + g2*dj1 + h0*aj  + h2*aj1;
            Q[2*j+1] = g1*dj1 + g3*dj2 + h1*aj1 + h3*aj2;
        }
        __builtin_amdgcn_wave_barrier();
    }
    // synth lev6: d6(Y+384), rec7(Q) -> rec6(128) in P[0..128)
    {
        const float h0=filt[24],h1=filt[25],h2=filt[26],h3=filt[27];
        const float g0=h3,g1=-h2,g2=h1,g3=-h0;
        if (lane < 64) {
            const int j = lane;
            const float dj=Y[384+j], dj1=Y[384+((j+1)&63)], dj2=Y[384+((j+2)&63)];
            const float aj=Q[j], aj1=Q[(j+1)&63], aj2=Q[(j+2)&63];
            P[2*j]   = g0*dj  + g2*dj1 + h0*aj  + h2*aj1;
            P[2*j+1] = g1*dj1 + g3*dj2 + h1*aj1 + h3*aj2;
        }
        __builtin_amdgcn_wave_barrier();
    }
    // synth lev5: d5(Y+256), rec6(P) -> rec5(256) in Q[0..256)
    {
        const float h0=filt[20],h1=filt[21],h2=filt[22],h3=filt[23];
        const float g0=h3,g1=-h2,g2=h1,g3=-h0;
        for (int j = lane; j < 128; j += 64) {
            const float dj=Y[256+j], dj1=Y[256+((j+1)&127)], dj2=Y[256+((j+2)&127)];
            const float aj=P[j], aj1=P[(j+1)&127], aj2=P[(j+2)&127];
            Q[2*j]   = g0*dj  + g2*dj1 + h0*aj  + h2*aj1;
            Q[2*j+1] = g1*dj1 + g3*dj2 + h1*aj1 + h3*aj2;
        }
        __builtin_amdgcn_wave_barrier();
    }
    // synth lev4: d4(Y), rec5(Q) -> rec4(512) straight to global staging
    {
        const float h0=filt[16],h1=filt[17],h2=filt[18],h3=filt[19];
        const float g0=h3,g1=-h2,g2=h1,g3=-h0;
        float2* __restrict__ st = reinterpret_cast<float2*>(out_rec + 512);
        for (int j = lane; j < 256; j += 64) {
            const float dj=Y[j], dj1=Y[(j+1)&255], dj2=Y[(j+2)&255];
            const float aj=Q[j], aj1=Q[(j+1)&255], aj2=Q[(j+2)&255];
            const float r0 = g0*dj  + g2*dj1 + h0*aj  + h2*aj1;
            const float r1 = g1*dj1 + g3*dj2 + h1*aj1 + h3*aj2;
            st[j] = make_float2(r0, r1);
        }
    }
}

// ---------------------------------------------------------------------------
// Kernel C: synthesis lev3..0. rec4 from staging (out_rec[512..1024)),
// d3..d0 from out_coef (L3-hot). rec ping-pongs in LDS; final write global.
// ---------------------------------------------------------------------------
__global__ __launch_bounds__(TPB) void despawn_synth(
    const float* __restrict__ scaling, float* __restrict__ out, int rows)
{
    __shared__ __align__(16) float LA[4096];  // 16 KB
    __shared__ __align__(16) float LB[4096];  // 16 KB
    __shared__ float filt[32];

    const int row = blockIdx.x;
    const int tid = threadIdx.x;
    if (tid < 32) filt[tid] = scaling[tid];
    bar_lds();

    float* __restrict__       out_rec  = out + (size_t)row * COLS;
    const float* __restrict__ out_coef = out + (size_t)rows * COLS + (size_t)row * COLS;

    // rec[2j]   = g0*d[j]   + g2*d[j+1] + h0*a[j]   + h2*a[j+1]
    // rec[2j+1] = g1*d[j+1] + g3*d[j+2] + h1*a[j+1] + h3*a[j+2]   (mod m)
#define SYNTH_BODY(d2, a2, dst4, toG)                                         \
    for (int p = tid; p < mp; p += TPB) {                                     \
        const float2 dv0 = (d2)[p];                                           \
        const float2 dv1 = (d2)[(p + 1) & mm];                                \
        const float2 av0 = (a2)[p];                                           \
        const float2 av1 = (a2)[(p + 1) & mm];                                \
        const float r0 = g0*dv0.x + g2*dv0.y + h0*av0.x + h2*av0.y;           \
        const float r1 = g1*dv0.y + g3*dv1.x + h1*av0.y + h3*av1.x;           \
        const float r2 = g0*dv0.y + g2*dv1.x + h0*av0.y + h2*av1.x;           \
        const float r3 = g1*dv1.x + g3*dv1.y + h1*av1.x + h3*av1.y;           \
        (dst4)[p] = make_float4(r0, r1, r2, r3);                              \
    }

    // lev3: m=512  a=rec4(global staging) d=d3(global) -> rec3(1024) in LB
    {
        const float h0=filt[12],h1=filt[13],h2=filt[14],h3=filt[15];
        const float g0=h3,g1=-h2,g2=h1,g3=-h0;
        const int mp = 256, mm = 255;
        const float2* __restrict__ d2 = reinterpret_cast<const float2*>(out_coef + 7168);
        const float2* __restrict__ a2 = reinterpret_cast<const float2*>(out_rec + 512);
        float4* dst4 = reinterpret_cast<float4*>(LB);
        SYNTH_BODY(d2, a2, dst4, false)
        bar_lds();
    }
    // lev2: m=1024  a=rec3(LB) d=d2(global) -> rec2(2048) in LA
    {
        const float h0=filt[8],h1=filt[9],h2=filt[10],h3=filt[11];
        const float g0=h3,g1=-h2,g2=h1,g3=-h0;
        const int mp = 512, mm = 511;
        const float2* __restrict__ d2 = reinterpret_cast<const float2*>(out_coef + 6144);
        const float2* a2 = reinterpret_cast<const float2*>(LB);
        float4* dst4 = reinterpret_cast<float4*>(LA);
        SYNTH_BODY(d2, a2, dst4, false)
        bar_lds();
    }
    // lev1: m=2048  a=rec2(LA) d=d1(global) -> rec1(4096) in LB
    {
        const float h0=filt[4],h1=filt[5],h2=filt[6],h3=filt[7];
        const float g0=h3,g1=-h2,g2=h1,g3=-h0;
        const int mp = 1024, mm = 1023;
        const float2* __restrict__ d2 = reinterpret_cast<const float2*>(out_coef + 4096);
        const float2* a2 = reinterpret_cast<const float2*>(LA);
        float4* dst4 = reinterpret_cast<float4*>(LB);
        SYNTH_BODY(d2, a2, dst4, false)
        bar_lds();
    }
    // lev0: m=4096  a=rec1(LB) d=d0(global) -> rec(8192) to global
    {
        const float h0=filt[0],h1=filt[1],h2=filt[2],h3=filt[3];
        const float g0=h3,g1=-h2,g2=h1,g3=-h0;
        const int mp = 2048, mm = 2047;
        const float2* __restrict__ d2 = reinterpret_cast<const float2*>(out_coef);
        const float2* a2 = reinterpret_cast<const float2*>(LB);
        float4* __restrict__ dst4 = reinterpret_cast<float4*>(out_rec);
        SYNTH_BODY(d2, a2, dst4, true)
    }
#undef SYNTH_BODY
}

extern "C" void kernel_launch(void* const* d_in, const int* in_sizes, int n_in,
                              void* d_out, int out_size, void* d_ws, size_t ws_size,
                              hipStream_t stream) {
    const float* x       = (const float*)d_in[0];
    const float* scaling = (const float*)d_in[1];
    float* out           = (float*)d_out;
    const int rows = in_sizes[0] / COLS;
    despawn_analysis<<<rows, TPB, 0, stream>>>(x, scaling, out, rows);
    despawn_synth<<<rows, TPB, 0, stream>>>(scaling, out, rows);
}